// Round 7
// baseline (326.281 us; speedup 1.0000x reference)
//
#include <hip/hip_runtime.h>
#include <stdint.h>

typedef short bf16x8 __attribute__((ext_vector_type(8)));
typedef float f32x4 __attribute__((ext_vector_type(4)));

__device__ __forceinline__ void async_cp16(const void* g, short* lds) {
  __builtin_amdgcn_global_load_lds(
      (const __attribute__((address_space(1))) void*)g,
      (__attribute__((address_space(3))) void*)lds, 16, 0, 0);
}

// tanh-approx GELU via sigmoid; |err| < ~1e-3 abs, threshold is 4.3e-2.
__device__ __forceinline__ float gelu_f(float v) {
  float z = 1.5957691216057308f * (v + 0.044715f * v * v * v);
  return __fdividef(v, 1.0f + __expf(-z));
}

__device__ __forceinline__ short f2bf(float x) {  // RNE f32->bf16
  uint32_t u = __float_as_uint(x);
  u += 0x7fffu + ((u >> 16) & 1u);
  return (short)(u >> 16);
}

// ---------------------------------------------------------------------------
// One-launch prep: fp32 -> bf16 cast of X + per-expert transposes of W1/W2.
// ---------------------------------------------------------------------------
__global__ __launch_bounds__(256)
void prep_all(const float* __restrict__ x, const float* __restrict__ w1,
              const float* __restrict__ w2, short* __restrict__ Xb,
              short* __restrict__ w1t, short* __restrict__ w2t)
{
  __shared__ __align__(16) short T[64][72];
  const int b = blockIdx.x;
  const int t = threadIdx.x;

  if (b < 2048) {                       // ---- X cast ----
    const int idx = (b * 256 + t) * 8;
    bf16x8 o;
#pragma unroll
    for (int u = 0; u < 8; ++u) o[u] = f2bf(x[idx + u]);
    *(bf16x8*)(Xb + idx) = o;
    return;
  }

  const float* src; short* dst; int e, r0, c0, R, C;
  if (b < 3072) {                       // ---- W1 ----
    int idx = b - 2048; e = idx >> 6; int rem = idx & 63;
    r0 = (rem >> 3) * 64; c0 = (rem & 7) * 64; R = 512; C = 512;
    src = w1; dst = w1t;
  } else {                              // ---- W2 ----
    int idx = b - 3072; e = idx >> 4; int rem = idx & 15;
    r0 = (rem >> 1) * 64; c0 = (rem & 1) * 64; R = 512; C = 128;
    src = w2; dst = w2t;
  }
  const float* s = src + (size_t)e * R * C;
  short* d       = dst + (size_t)e * R * C;
  const int i = t >> 3, j8 = t & 7;
#pragma unroll
  for (int p = 0; p < 2; ++p) {
    int ii = i + p * 32;
#pragma unroll
    for (int u = 0; u < 8; ++u)
      T[ii][j8 * 8 + u] = f2bf(s[(size_t)(r0 + ii) * C + c0 + j8 * 8 + u]);
  }
  __syncthreads();
#pragma unroll
  for (int p = 0; p < 2; ++p) {
    int ii = i + p * 32;
    bf16x8 v;
#pragma unroll
    for (int u = 0; u < 8; ++u) v[u] = T[j8 * 8 + u][ii];
    *(bf16x8*)(d + (size_t)(c0 + ii) * R + r0 + j8 * 8) = v;
  }
}

// ---------------------------------------------------------------------------
// Fused experts. Block = 128-token tile x 1 expert, 4 waves (2x2 of 64x64).
// Async global_load_lds staging, double-buffered K=32 slices, XOR quad swizzle.
// LDS ALIASING for 3 blocks/CU: HL overlaps Xs0/Xs1 (phase-disjoint lifetimes;
// barriers added at the phase boundaries). 51.2 KB total.
// staged==1: O = ws bf16 [16 e][8192 row][128 d4] (coalesced).
// staged==0: O = out fp32 [row][d4][16 e] (strided fallback).
// ---------------------------------------------------------------------------
__global__ __launch_bounds__(256, 3)
void moe_kernel(const short* __restrict__ Xb, const short* __restrict__ W1T,
                const short* __restrict__ W2T, void* __restrict__ O, int staged)
{
  __shared__ __align__(16) short SM[25600];        // 51.2 KB
  short* const Ws0 = SM;                           // [128][32]
  short* const Ws1 = SM + 4096;
  short* const Xs0 = SM + 8192;                    // aliased by HL
  short* const Xs1 = SM + 12288;                   // aliased by HL
  short* const HL  = SM + 8192;                    // [128][136], phase-2 only

  const int tid = threadIdx.x;
  const int l = tid & 63, w = tid >> 6;
  const int wm = w & 1, wn = w >> 1;
  const int e = blockIdx.x & 15;
  const int tile = blockIdx.x >> 4;

  // staging lane constants (lane -> base + lane*16B, packed [row][32 shorts])
  const int lrow = l >> 2, lq = l & 3;
  int ldso[2];
  const char *xg[2], *w1g[2], *w2g[2];
#pragma unroll
  for (int c = 0; c < 2; ++c) {
    int prow = w * 32 + c * 16 + lrow;                      // 0..127
    int qg = lq ^ ((prow >> 1) & 3);                        // XOR quad swizzle
    ldso[c] = (w * 32 + c * 16) * 32;
    xg[c]  = (const char*)Xb  + (size_t)(tile * 128 + prow) * 1024 + qg * 16;
    w1g[c] = (const char*)W1T + (size_t)e * 524288 + (size_t)prow * 1024 + qg * 16;
    w2g[c] = (const char*)W2T + (size_t)e * 131072 + (size_t)prow * 1024 + qg * 16;
  }

  // consumer lane constants (shorts); slot undoes the swizzle
  const int lm = l & 15;
  const int slot = (l >> 4) ^ ((lm >> 1) & 3);
  const int aoff = (wm * 64 + lm) * 32 + slot * 8;
  const int boff = (wn * 64 + lm) * 32 + slot * 8;
  const int hro  = (wm * 64 + lm) * 136 + (l >> 4) * 8;
  const int hwo  = (wm * 64 + (l >> 4) * 4) * 136 + wn * 64 + lm;

  f32x4 acc2[4][4];
#pragma unroll
  for (int i = 0; i < 4; ++i)
#pragma unroll
    for (int j = 0; j < 4; ++j) acc2[i][j] = (f32x4){0.f, 0.f, 0.f, 0.f};

  // prologue: stage hc=0, kk=0 into buf0
#pragma unroll
  for (int c = 0; c < 2; ++c) {
    async_cp16(xg[c],  Xs0 + ldso[c]);
    async_cp16(w1g[c], Ws0 + ldso[c]);
  }

  for (int hc = 0; hc < 4; ++hc) {
    f32x4 acc1[4][4];
#pragma unroll
    for (int i = 0; i < 4; ++i)
#pragma unroll
      for (int j = 0; j < 4; ++j) acc1[i][j] = (f32x4){0.f, 0.f, 0.f, 0.f};

    const size_t w1hc = (size_t)hc * 131072;   // 128 h-rows * 1024B

    // ---- phase 1: hidden[:, hc*128:+128] = X * W1, K=512 in 16 slices ----
#pragma unroll
    for (int kk = 0; kk < 16; ++kk) {
      __syncthreads();                         // drains vmcnt: current bufs ready
      if (kk < 15) {
        short* xb = ((kk + 1) & 1) ? Xs1 : Xs0;
        short* wb = ((kk + 1) & 1) ? Ws1 : Ws0;
#pragma unroll
        for (int c = 0; c < 2; ++c) {
          async_cp16(xg[c] + (kk + 1) * 64,         xb + ldso[c]);
          async_cp16(w1g[c] + w1hc + (kk + 1) * 64, wb + ldso[c]);
        }
      } else {                                 // prefetch phase-2 s=0 into Ws0
#pragma unroll
        for (int c = 0; c < 2; ++c)
          async_cp16(w2g[c] + hc * 256, Ws0 + ldso[c]);
      }
      const short* xb = (kk & 1) ? Xs1 : Xs0;
      const short* wb = (kk & 1) ? Ws1 : Ws0;
      bf16x8 af[4], bfr[4];
#pragma unroll
      for (int t = 0; t < 4; ++t) af[t]  = *(const bf16x8*)(xb + aoff + t * 512);
#pragma unroll
      for (int t = 0; t < 4; ++t) bfr[t] = *(const bf16x8*)(wb + boff + t * 512);
#pragma unroll
      for (int i = 0; i < 4; ++i)
#pragma unroll
        for (int j = 0; j < 4; ++j)
          acc1[i][j] = __builtin_amdgcn_mfma_f32_16x16x32_bf16(af[i], bfr[j], acc1[i][j], 0, 0, 0);
    }

    __syncthreads();   // ALIAS GUARD: all waves' kk=15 reads of Xs1 done before HL writes

    // ---- GELU + spill hidden chunk to HL (aliases Xs bufs) ----
#pragma unroll
    for (int i = 0; i < 4; ++i)
#pragma unroll
      for (int j = 0; j < 4; ++j)
#pragma unroll
        for (int r = 0; r < 4; ++r)
          HL[hwo + i * 2176 + r * 136 + j * 16] = f2bf(gelu_f(acc1[i][j][r]));

    // ---- phase 2: acc2 += gelu(chunk) * W2 slice, K=128 in 4 slices ----
#pragma unroll
    for (int s = 0; s < 4; ++s) {
      __syncthreads();                         // HL writes + W2 slice staged
      if (s < 3) {
        short* wb = ((s + 1) & 1) ? Ws1 : Ws0;
#pragma unroll
        for (int c = 0; c < 2; ++c)
          async_cp16(w2g[c] + hc * 256 + (s + 1) * 64, wb + ldso[c]);
      }
      const short* wb = (s & 1) ? Ws1 : Ws0;
      bf16x8 af[4], bfr[4];
#pragma unroll
      for (int t = 0; t < 4; ++t) af[t]  = *(const bf16x8*)(HL + hro + t * 2176 + s * 32);
#pragma unroll
      for (int t = 0; t < 4; ++t) bfr[t] = *(const bf16x8*)(wb + boff + t * 512);
#pragma unroll
      for (int i = 0; i < 4; ++i)
#pragma unroll
        for (int j = 0; j < 4; ++j)
          acc2[i][j] = __builtin_amdgcn_mfma_f32_16x16x32_bf16(af[i], bfr[j], acc2[i][j], 0, 0, 0);
    }

    if (hc < 3) {
      __syncthreads();   // ALIAS GUARD: HL reads done before next-hc staging into Xs0
#pragma unroll
      for (int c = 0; c < 2; ++c) {
        async_cp16(xg[c],                              Xs0 + ldso[c]);
        async_cp16(w1g[c] + (size_t)(hc + 1) * 131072, Ws0 + ldso[c]);
      }
    }
  }

  // ---- epilogue ----
  const int d4 = wn * 64 + lm;
  const int lqr = (l >> 4) * 4;
  if (staged) {  // coalesced bf16: OUTs[e][row][d4]
    unsigned short* Ob = (unsigned short*)O;
    const size_t base = ((size_t)e * 8192 + tile * 128 + wm * 64 + lqr) * 128 + d4;
#pragma unroll
    for (int i = 0; i < 4; ++i)
#pragma unroll
      for (int r = 0; r < 4; ++r)
#pragma unroll
        for (int j = 0; j < 4; ++j)
          Ob[base + (size_t)(i * 16 + r) * 128 + j * 16] = (unsigned short)f2bf(acc2[i][j][r]);
  } else {       // direct strided fp32 fallback
    float* Of = (float*)O;
    const size_t rowb = (size_t)tile * 128 + wm * 64 + lqr;
    const size_t base = (rowb * 128 + d4) * 16 + e;
#pragma unroll
    for (int i = 0; i < 4; ++i)
#pragma unroll
      for (int r = 0; r < 4; ++r)
#pragma unroll
        for (int j = 0; j < 4; ++j)
          Of[base + (size_t)(i * 16 + r) * 2048 + j * 256] = acc2[i][j][r];
  }
}

// ---------------------------------------------------------------------------
// Permute: OUT[row][d4*16+e] (fp32) = OUTs[e][row][d4] (bf16). Block = 8 rows.
// LDS T[8 r][16 e][132 d4] fp32.
// ---------------------------------------------------------------------------
__global__ __launch_bounds__(256, 2)
void permute_kernel(const unsigned short* __restrict__ OUTs, float* __restrict__ OUT)
{
  __shared__ float T[8 * 16 * 132];     // 67.6 KB
  const int t = threadIdx.x;
  const int r0 = blockIdx.x * 8;
#pragma unroll
  for (int it = 0; it < 8; ++it) {
    int v = it * 256 + t;                       // bf16x8-id, [0,2048)
    int e = v >> 7, rem = v & 127, r = rem >> 4, q8 = rem & 15;
    bf16x8 d = *(const bf16x8*)(OUTs + ((size_t)e * 8192 + r0 + r) * 128 + q8 * 8);
#pragma unroll
    for (int u = 0; u < 8; ++u)
      T[(r * 16 + e) * 132 + q8 * 8 + u] =
          __uint_as_float(((uint32_t)(unsigned short)d[u]) << 16);
  }
  __syncthreads();
#pragma unroll
  for (int it = 0; it < 16; ++it) {
    int u = it * 256 + t;                       // vec4 id, [0,4096)
    int r = u >> 9;                             // [0,8)
    int c4 = (u & 511) * 4;                     // [0,2048)
    int d4 = c4 >> 4, e0 = c4 & 15;
    f32x4 o;
#pragma unroll
    for (int i = 0; i < 4; ++i) o[i] = T[(r * 16 + e0 + i) * 132 + d4];
    *(f32x4*)(OUT + (size_t)(r0 + r) * 2048 + c4) = o;
  }
}

extern "C" void kernel_launch(void* const* d_in, const int* in_sizes, int n_in,
                              void* d_out, int out_size, void* d_ws, size_t ws_size,
                              hipStream_t stream)
{
  const float* x  = (const float*)d_in[0];   // fp32 [8192][512]
  const float* w1 = (const float*)d_in[1];   // fp32 [16][512][512]
  const float* w2 = (const float*)d_in[2];   // fp32 [16][512][128]
  float* out = (float*)d_out;                // fp32 [8192][128][16]

  short* Xb  = (short*)d_ws;                 // 8.39 MB
  short* w1t = Xb + 4194304;                 // 8.39 MB
  short* w2t = w1t + 4194304;                // 2.10 MB
  unsigned short* OUTs = (unsigned short*)((char*)d_ws + 18874368);  // bf16, 33.5 MB
  const bool staged = ws_size >= 52428800ULL;

  prep_all<<<dim3(3328), 256, 0, stream>>>(x, w1, w2, Xb, w1t, w2t);
  moe_kernel<<<dim3(1024), 256, 0, stream>>>(Xb, w1t, w2t,
                                             staged ? (void*)OUTs : (void*)out,
                                             staged ? 1 : 0);
  if (staged)
    permute_kernel<<<dim3(1024), 256, 0, stream>>>(OUTs, out);
}

// Round 8
// 240.834 us; speedup vs baseline: 1.3548x; 1.3548x over previous
//
#include <hip/hip_runtime.h>
#include <stdint.h>

typedef short bf16x8 __attribute__((ext_vector_type(8)));
typedef float f32x4 __attribute__((ext_vector_type(4)));

__device__ __forceinline__ void async_cp16(const void* g, short* lds) {
  __builtin_amdgcn_global_load_lds(
      (const __attribute__((address_space(1))) void*)g,
      (__attribute__((address_space(3))) void*)lds, 16, 0, 0);
}

// tanh-approx GELU via sigmoid; |err| < ~1e-3 abs, threshold is 4.3e-2.
__device__ __forceinline__ float gelu_f(float v) {
  float z = 1.5957691216057308f * (v + 0.044715f * v * v * v);
  return __fdividef(v, 1.0f + __expf(-z));
}

__device__ __forceinline__ short f2bf(float x) {  // RNE f32->bf16
  uint32_t u = __float_as_uint(x);
  u += 0x7fffu + ((u >> 16) & 1u);
  return (short)(u >> 16);
}

// ---------------------------------------------------------------------------
// One-launch prep: fp32 -> bf16 cast of X + per-expert transposes of W1/W2.
// ---------------------------------------------------------------------------
__global__ __launch_bounds__(256)
void prep_all(const float* __restrict__ x, const float* __restrict__ w1,
              const float* __restrict__ w2, short* __restrict__ Xb,
              short* __restrict__ w1t, short* __restrict__ w2t)
{
  __shared__ __align__(16) short T[64][72];
  const int b = blockIdx.x;
  const int t = threadIdx.x;

  if (b < 2048) {                       // ---- X cast ----
    const int idx = (b * 256 + t) * 8;
    bf16x8 o;
#pragma unroll
    for (int u = 0; u < 8; ++u) o[u] = f2bf(x[idx + u]);
    *(bf16x8*)(Xb + idx) = o;
    return;
  }

  const float* src; short* dst; int e, r0, c0, R, C;
  if (b < 3072) {                       // ---- W1 ----
    int idx = b - 2048; e = idx >> 6; int rem = idx & 63;
    r0 = (rem >> 3) * 64; c0 = (rem & 7) * 64; R = 512; C = 512;
    src = w1; dst = w1t;
  } else {                              // ---- W2 ----
    int idx = b - 3072; e = idx >> 4; int rem = idx & 15;
    r0 = (rem >> 1) * 64; c0 = (rem & 1) * 64; R = 512; C = 128;
    src = w2; dst = w2t;
  }
  const float* s = src + (size_t)e * R * C;
  short* d       = dst + (size_t)e * R * C;
  const int i = t >> 3, j8 = t & 7;
#pragma unroll
  for (int p = 0; p < 2; ++p) {
    int ii = i + p * 32;
#pragma unroll
    for (int u = 0; u < 8; ++u)
      T[ii][j8 * 8 + u] = f2bf(s[(size_t)(r0 + ii) * C + c0 + j8 * 8 + u]);
  }
  __syncthreads();
#pragma unroll
  for (int p = 0; p < 2; ++p) {
    int ii = i + p * 32;
    bf16x8 v;
#pragma unroll
    for (int u = 0; u < 8; ++u) v[u] = T[j8 * 8 + u][ii];
    *(bf16x8*)(d + (size_t)(c0 + ii) * R + r0 + j8 * 8) = v;
  }
}

// ---------------------------------------------------------------------------
// Fused experts. Block = 128-token tile x 1 expert, 4 waves (2x2 of 64x64).
// BK=64 double-buffered async staging (32 MFMA per barrier; ~50 barriers/blk).
// Global-side XOR quad swizzle qg=(l&7)^(l>>3); consumer un-swizzles with
// lane-constant offsets. HL aliases Xs0/Xs1 (phase-disjoint + guards).
// LDS 66 KB -> 2 blocks/CU; launch_bounds(256,2) -> no VGPR spill (R7 lesson).
// ---------------------------------------------------------------------------
__global__ __launch_bounds__(256, 2)
void moe_kernel(const short* __restrict__ Xb, const short* __restrict__ W1T,
                const short* __restrict__ W2T, void* __restrict__ O, int staged)
{
  __shared__ __align__(16) short SM[33792];        // 67.6 KB
  short* const Ws0 = SM;                           // [128 rows][64 k]
  short* const Ws1 = SM + 8192;
  short* const Xs0 = SM + 16384;                   // aliased by HL
  short* const Xs1 = SM + 24576;                   // aliased by HL
  short* const HL  = SM + 16384;                   // [128][136], phase-2 only

  const int tid = threadIdx.x;
  const int l = tid & 63, w = tid >> 6;
  const int wm = w & 1, wn = w >> 1;
  const int e = blockIdx.x & 15;
  const int tile = blockIdx.x >> 4;

  // ---- staging lane constants: 4 issues/thread, 8-quad rows, global swizzle ----
  const int qg = (l & 7) ^ (l >> 3);               // global quad to fetch
  int ldso[4];                                      // LDS chunk base (shorts)
  const char *xg[4], *w1g[4], *w2g[4];
#pragma unroll
  for (int c = 0; c < 4; ++c) {
    int rowb = c * 32 + w * 8;                     // wave-uniform
    int prow = rowb + (l >> 3);                    // 0..127
    ldso[c] = rowb * 64;
    xg[c]  = (const char*)Xb  + (size_t)(tile * 128 + prow) * 1024 + qg * 16;
    w1g[c] = (const char*)W1T + (size_t)e * 524288 + (size_t)prow * 1024 + qg * 16;
    w2g[c] = (const char*)W2T + (size_t)e * 131072 + (size_t)prow * 1024 + qg * 16;
  }

  // ---- consumer lane constants (shorts); un-swizzle slot = quad ^ (row&7) ----
  const int lm = l & 15, lq = l >> 4;
  const int mx = lm & 7;
  const int aq0 = ((0 * 4 + lq) ^ mx) * 8, aq1 = ((1 * 4 + lq) ^ mx) * 8;
  const int arow = (wm * 64 + lm) * 64;            // A base in Xs
  const int brow = (wn * 64 + lm) * 64;            // B base in Ws
  const int hro  = (wm * 64 + lm) * 136 + lq * 8;  // A base in HL (no swizzle)
  const int hwo  = (wm * 64 + lq * 4) * 136 + wn * 64 + lm;  // C->HL write

  f32x4 acc2[4][4];
#pragma unroll
  for (int i = 0; i < 4; ++i)
#pragma unroll
    for (int j = 0; j < 4; ++j) acc2[i][j] = (f32x4){0.f, 0.f, 0.f, 0.f};

  // prologue: stage hc=0, kk=0 into buf0
#pragma unroll
  for (int c = 0; c < 4; ++c) {
    async_cp16(xg[c],  Xs0 + ldso[c]);
    async_cp16(w1g[c], Ws0 + ldso[c]);
  }

  for (int hc = 0; hc < 4; ++hc) {
    f32x4 acc1[4][4];
#pragma unroll
    for (int i = 0; i < 4; ++i)
#pragma unroll
      for (int j = 0; j < 4; ++j) acc1[i][j] = (f32x4){0.f, 0.f, 0.f, 0.f};

    const size_t w1hc = (size_t)hc * 131072;       // 128 h-rows * 1024 B

    // ---- phase 1: hidden[:, hc*128:+128] = X * W1, K=512 in 8 BK=64 slices ----
#pragma unroll
    for (int kk = 0; kk < 8; ++kk) {
      __syncthreads();                             // vmcnt drain: bufs ready
      if (kk < 7) {
        short* xb = ((kk + 1) & 1) ? Xs1 : Xs0;
        short* wb = ((kk + 1) & 1) ? Ws1 : Ws0;
#pragma unroll
        for (int c = 0; c < 4; ++c) {
          async_cp16(xg[c] + (kk + 1) * 128,         xb + ldso[c]);
          async_cp16(w1g[c] + w1hc + (kk + 1) * 128, wb + ldso[c]);
        }
      } else {                                     // prefetch phase-2 s=0 W2 -> Ws0
#pragma unroll
        for (int c = 0; c < 4; ++c)
          async_cp16(w2g[c] + hc * 256, Ws0 + ldso[c]);
      }
      const short* xb = (kk & 1) ? Xs1 : Xs0;
      const short* wb = (kk & 1) ? Ws1 : Ws0;
#pragma unroll
      for (int u = 0; u < 2; ++u) {                // two k-steps of 32
        const int qo = u ? aq1 : aq0;
        bf16x8 af[4], bfr[4];
#pragma unroll
        for (int t = 0; t < 4; ++t) af[t]  = *(const bf16x8*)(xb + arow + t * 1024 + qo);
#pragma unroll
        for (int t = 0; t < 4; ++t) bfr[t] = *(const bf16x8*)(wb + brow + t * 1024 + qo);
#pragma unroll
        for (int i = 0; i < 4; ++i)
#pragma unroll
          for (int j = 0; j < 4; ++j)
            acc1[i][j] = __builtin_amdgcn_mfma_f32_16x16x32_bf16(af[i], bfr[j], acc1[i][j], 0, 0, 0);
      }
    }

    __syncthreads();   // ALIAS GUARD: kk=7 reads of Xs1 done before HL writes

    // ---- GELU + spill hidden chunk to HL (aliases Xs bufs) ----
#pragma unroll
    for (int i = 0; i < 4; ++i)
#pragma unroll
      for (int j = 0; j < 4; ++j)
#pragma unroll
        for (int r = 0; r < 4; ++r)
          HL[hwo + i * 2176 + r * 136 + j * 16] = f2bf(gelu_f(acc1[i][j][r]));

    // ---- phase 2: acc2 += gelu(chunk) * W2 slice, K=128 in 2 BK=64 slices ----
#pragma unroll
    for (int s = 0; s < 2; ++s) {
      __syncthreads();                             // HL writes + W2 slice staged
      if (s == 0) {                                // prefetch W2 s=1 -> Ws1
#pragma unroll
        for (int c = 0; c < 4; ++c)
          async_cp16(w2g[c] + hc * 256 + 128, Ws1 + ldso[c]);
      } else if (hc < 3) {                         // prefetch next-hc W1 kk=0 -> Ws0
#pragma unroll
        for (int c = 0; c < 4; ++c)
          async_cp16(w1g[c] + (size_t)(hc + 1) * 131072, Ws0 + ldso[c]);
      }
      const short* wb = (s & 1) ? Ws1 : Ws0;
#pragma unroll
      for (int u = 0; u < 2; ++u) {
        const int qo = u ? aq1 : aq0;
        bf16x8 af[4], bfr[4];
#pragma unroll
        for (int t = 0; t < 4; ++t) af[t]  = *(const bf16x8*)(HL + hro + t * 2176 + s * 64 + u * 32);
#pragma unroll
        for (int t = 0; t < 4; ++t) bfr[t] = *(const bf16x8*)(wb + brow + t * 1024 + qo);
#pragma unroll
        for (int i = 0; i < 4; ++i)
#pragma unroll
          for (int j = 0; j < 4; ++j)
            acc2[i][j] = __builtin_amdgcn_mfma_f32_16x16x32_bf16(af[i], bfr[j], acc2[i][j], 0, 0, 0);
      }
    }

    if (hc < 3) {
      __syncthreads();   // ALIAS GUARD: HL reads done before staging into Xs0
#pragma unroll
      for (int c = 0; c < 4; ++c)
        async_cp16(xg[c], Xs0 + ldso[c]);
    }
  }

  // ---- epilogue ----
  const int d4 = wn * 64 + lm;
  const int lqr = lq * 4;
  if (staged) {  // coalesced bf16: OUTs[e][row][d4]
    unsigned short* Ob = (unsigned short*)O;
    const size_t base = ((size_t)e * 8192 + tile * 128 + wm * 64 + lqr) * 128 + d4;
#pragma unroll
    for (int i = 0; i < 4; ++i)
#pragma unroll
      for (int r = 0; r < 4; ++r)
#pragma unroll
        for (int j = 0; j < 4; ++j)
          Ob[base + (size_t)(i * 16 + r) * 128 + j * 16] = (unsigned short)f2bf(acc2[i][j][r]);
  } else {       // direct strided fp32 fallback
    float* Of = (float*)O;
    const size_t rowb = (size_t)tile * 128 + wm * 64 + lqr;
    const size_t base = (rowb * 128 + d4) * 16 + e;
#pragma unroll
    for (int i = 0; i < 4; ++i)
#pragma unroll
      for (int r = 0; r < 4; ++r)
#pragma unroll
        for (int j = 0; j < 4; ++j)
          Of[base + (size_t)(i * 16 + r) * 2048 + j * 256] = acc2[i][j][r];
  }
}

// ---------------------------------------------------------------------------
// Permute: OUT[row][d4*16+e] (fp32) = OUTs[e][row][d4] (bf16). Block = 8 rows.
// ---------------------------------------------------------------------------
__global__ __launch_bounds__(256, 2)
void permute_kernel(const unsigned short* __restrict__ OUTs, float* __restrict__ OUT)
{
  __shared__ float T[8 * 16 * 132];     // 67.6 KB
  const int t = threadIdx.x;
  const int r0 = blockIdx.x * 8;
#pragma unroll
  for (int it = 0; it < 8; ++it) {
    int v = it * 256 + t;                       // bf16x8-id, [0,2048)
    int e = v >> 7, rem = v & 127, r = rem >> 4, q8 = rem & 15;
    bf16x8 d = *(const bf16x8*)(OUTs + ((size_t)e * 8192 + r0 + r) * 128 + q8 * 8);
#pragma unroll
    for (int u = 0; u < 8; ++u)
      T[(r * 16 + e) * 132 + q8 * 8 + u] =
          __uint_as_float(((uint32_t)(unsigned short)d[u]) << 16);
  }
  __syncthreads();
#pragma unroll
  for (int it = 0; it < 16; ++it) {
    int u = it * 256 + t;                       // vec4 id, [0,4096)
    int r = u >> 9;                             // [0,8)
    int c4 = (u & 511) * 4;                     // [0,2048)
    int d4 = c4 >> 4, e0 = c4 & 15;
    f32x4 o;
#pragma unroll
    for (int i = 0; i < 4; ++i) o[i] = T[(r * 16 + e0 + i) * 132 + d4];
    *(f32x4*)(OUT + (size_t)(r0 + r) * 2048 + c4) = o;
  }
}

extern "C" void kernel_launch(void* const* d_in, const int* in_sizes, int n_in,
                              void* d_out, int out_size, void* d_ws, size_t ws_size,
                              hipStream_t stream)
{
  const float* x  = (const float*)d_in[0];   // fp32 [8192][512]
  const float* w1 = (const float*)d_in[1];   // fp32 [16][512][512]
  const float* w2 = (const float*)d_in[2];   // fp32 [16][512][128]
  float* out = (float*)d_out;                // fp32 [8192][128][16]

  short* Xb  = (short*)d_ws;                 // 8.39 MB
  short* w1t = Xb + 4194304;                 // 8.39 MB
  short* w2t = w1t + 4194304;                // 2.10 MB
  unsigned short* OUTs = (unsigned short*)((char*)d_ws + 18874368);  // bf16, 33.5 MB
  const bool staged = ws_size >= 52428800ULL;

  prep_all<<<dim3(3328), 256, 0, stream>>>(x, w1, w2, Xb, w1t, w2t);
  moe_kernel<<<dim3(1024), 256, 0, stream>>>(Xb, w1t, w2t,
                                             staged ? (void*)OUTs : (void*)out,
                                             staged ? 1 : 0);
  if (staged)
    permute_kernel<<<dim3(1024), 256, 0, stream>>>(OUTs, out);
}

// Round 9
// 224.376 us; speedup vs baseline: 1.4542x; 1.0734x over previous
//
#include <hip/hip_runtime.h>
#include <stdint.h>

typedef short bf16x8 __attribute__((ext_vector_type(8)));
typedef float f32x4 __attribute__((ext_vector_type(4)));

__device__ __forceinline__ void async_cp16(const void* g, short* lds) {
  __builtin_amdgcn_global_load_lds(
      (const __attribute__((address_space(1))) void*)g,
      (__attribute__((address_space(3))) void*)lds, 16, 0, 0);
}

// tanh-approx GELU via sigmoid; |err| < ~1e-3 abs, threshold is 4.3e-2.
__device__ __forceinline__ float gelu_f(float v) {
  float z = 1.5957691216057308f * (v + 0.044715f * v * v * v);
  return __fdividef(v, 1.0f + __expf(-z));
}

__device__ __forceinline__ short f2bf(float x) {  // RNE f32->bf16
  uint32_t u = __float_as_uint(x);
  u += 0x7fffu + ((u >> 16) & 1u);
  return (short)(u >> 16);
}

// ---------------------------------------------------------------------------
// One-launch prep: fp32 -> bf16 cast of X + per-expert transposes of W1/W2.
// ---------------------------------------------------------------------------
__global__ __launch_bounds__(256)
void prep_all(const float* __restrict__ x, const float* __restrict__ w1,
              const float* __restrict__ w2, short* __restrict__ Xb,
              short* __restrict__ w1t, short* __restrict__ w2t)
{
  __shared__ __align__(16) short T[64][72];
  const int b = blockIdx.x;
  const int t = threadIdx.x;

  if (b < 2048) {                       // ---- X cast ----
    const int idx = (b * 256 + t) * 8;
    bf16x8 o;
#pragma unroll
    for (int u = 0; u < 8; ++u) o[u] = f2bf(x[idx + u]);
    *(bf16x8*)(Xb + idx) = o;
    return;
  }

  const float* src; short* dst; int e, r0, c0, R, C;
  if (b < 3072) {                       // ---- W1 ----
    int idx = b - 2048; e = idx >> 6; int rem = idx & 63;
    r0 = (rem >> 3) * 64; c0 = (rem & 7) * 64; R = 512; C = 512;
    src = w1; dst = w1t;
  } else {                              // ---- W2 ----
    int idx = b - 3072; e = idx >> 4; int rem = idx & 15;
    r0 = (rem >> 1) * 64; c0 = (rem & 1) * 64; R = 512; C = 128;
    src = w2; dst = w2t;
  }
  const float* s = src + (size_t)e * R * C;
  short* d       = dst + (size_t)e * R * C;
  const int i = t >> 3, j8 = t & 7;
#pragma unroll
  for (int p = 0; p < 2; ++p) {
    int ii = i + p * 32;
#pragma unroll
    for (int u = 0; u < 8; ++u)
      T[ii][j8 * 8 + u] = f2bf(s[(size_t)(r0 + ii) * C + c0 + j8 * 8 + u]);
  }
  __syncthreads();
#pragma unroll
  for (int p = 0; p < 2; ++p) {
    int ii = i + p * 32;
    bf16x8 v;
#pragma unroll
    for (int u = 0; u < 8; ++u) v[u] = T[j8 * 8 + u][ii];
    *(bf16x8*)(d + (size_t)(c0 + ii) * R + r0 + j8 * 8) = v;
  }
}

// ---------------------------------------------------------------------------
// Fused experts. Block = 128-token tile x 1 expert, 4 waves (2x2 of 64x64).
// R6's HW-proven BK=32 double-buffered async body + R7's HW-proven 51.2 KB
// aliased LDS (HL overlaps Xs0/Xs1, phase-disjoint + guards).
// launch_bounds(256,2): natural VGPR ~128 -> LDS (51.2 KB) limits to
// 3 blocks/CU (R7 lesson: asking (256,3) triggers 84-VGPR tier + spills).
// Block decode e-outer: consecutive blocks = same expert -> per-XCD L2
// working set ~3 MB (< 4 MB) instead of ~4.5 MB thrash.
// staged==1: O = ws bf16 [16 e][8192 row][128 d4] (coalesced).
// staged==0: O = out fp32 [row][d4][16 e] (strided fallback).
// ---------------------------------------------------------------------------
__global__ __launch_bounds__(256, 2)
void moe_kernel(const short* __restrict__ Xb, const short* __restrict__ W1T,
                const short* __restrict__ W2T, void* __restrict__ O, int staged)
{
  __shared__ __align__(16) short SM[25600];        // 51.2 KB
  short* const Ws0 = SM;                           // [128][32]
  short* const Ws1 = SM + 4096;
  short* const Xs0 = SM + 8192;                    // aliased by HL
  short* const Xs1 = SM + 12288;                   // aliased by HL
  short* const HL  = SM + 8192;                    // [128][136], phase-2 only

  const int tid = threadIdx.x;
  const int l = tid & 63, w = tid >> 6;
  const int wm = w & 1, wn = w >> 1;
  const int e    = blockIdx.x >> 6;     // e-outer (L2 locality per XCD)
  const int tile = blockIdx.x & 63;

  // staging lane constants (lane -> base + lane*16B, packed [row][32 shorts])
  const int lrow = l >> 2, lq = l & 3;
  int ldso[2];
  const char *xg[2], *w1g[2], *w2g[2];
#pragma unroll
  for (int c = 0; c < 2; ++c) {
    int prow = w * 32 + c * 16 + lrow;                      // 0..127
    int qg = lq ^ ((prow >> 1) & 3);                        // XOR quad swizzle
    ldso[c] = (w * 32 + c * 16) * 32;
    xg[c]  = (const char*)Xb  + (size_t)(tile * 128 + prow) * 1024 + qg * 16;
    w1g[c] = (const char*)W1T + (size_t)e * 524288 + (size_t)prow * 1024 + qg * 16;
    w2g[c] = (const char*)W2T + (size_t)e * 131072 + (size_t)prow * 1024 + qg * 16;
  }

  // consumer lane constants (shorts); slot undoes the swizzle
  const int lm = l & 15;
  const int slot = (l >> 4) ^ ((lm >> 1) & 3);
  const int aoff = (wm * 64 + lm) * 32 + slot * 8;
  const int boff = (wn * 64 + lm) * 32 + slot * 8;
  const int hro  = (wm * 64 + lm) * 136 + (l >> 4) * 8;
  const int hwo  = (wm * 64 + (l >> 4) * 4) * 136 + wn * 64 + lm;

  f32x4 acc2[4][4];
#pragma unroll
  for (int i = 0; i < 4; ++i)
#pragma unroll
    for (int j = 0; j < 4; ++j) acc2[i][j] = (f32x4){0.f, 0.f, 0.f, 0.f};

  // prologue: stage hc=0, kk=0 into buf0
#pragma unroll
  for (int c = 0; c < 2; ++c) {
    async_cp16(xg[c],  Xs0 + ldso[c]);
    async_cp16(w1g[c], Ws0 + ldso[c]);
  }

  for (int hc = 0; hc < 4; ++hc) {
    f32x4 acc1[4][4];
#pragma unroll
    for (int i = 0; i < 4; ++i)
#pragma unroll
      for (int j = 0; j < 4; ++j) acc1[i][j] = (f32x4){0.f, 0.f, 0.f, 0.f};

    const size_t w1hc = (size_t)hc * 131072;   // 128 h-rows * 1024B

    // ---- phase 1: hidden[:, hc*128:+128] = X * W1, K=512 in 16 slices ----
#pragma unroll
    for (int kk = 0; kk < 16; ++kk) {
      __syncthreads();                         // drains vmcnt: current bufs ready
      if (kk < 15) {
        short* xb = ((kk + 1) & 1) ? Xs1 : Xs0;
        short* wb = ((kk + 1) & 1) ? Ws1 : Ws0;
#pragma unroll
        for (int c = 0; c < 2; ++c) {
          async_cp16(xg[c] + (kk + 1) * 64,         xb + ldso[c]);
          async_cp16(w1g[c] + w1hc + (kk + 1) * 64, wb + ldso[c]);
        }
      } else {                                 // prefetch phase-2 s=0 into Ws0
#pragma unroll
        for (int c = 0; c < 2; ++c)
          async_cp16(w2g[c] + hc * 256, Ws0 + ldso[c]);
      }
      const short* xb = (kk & 1) ? Xs1 : Xs0;
      const short* wb = (kk & 1) ? Ws1 : Ws0;
      bf16x8 af[4], bfr[4];
#pragma unroll
      for (int t = 0; t < 4; ++t) af[t]  = *(const bf16x8*)(xb + aoff + t * 512);
#pragma unroll
      for (int t = 0; t < 4; ++t) bfr[t] = *(const bf16x8*)(wb + boff + t * 512);
#pragma unroll
      for (int i = 0; i < 4; ++i)
#pragma unroll
        for (int j = 0; j < 4; ++j)
          acc1[i][j] = __builtin_amdgcn_mfma_f32_16x16x32_bf16(af[i], bfr[j], acc1[i][j], 0, 0, 0);
    }

    __syncthreads();   // ALIAS GUARD: kk=15 reads of Xs1 done before HL writes

    // ---- GELU + spill hidden chunk to HL (aliases Xs bufs) ----
#pragma unroll
    for (int i = 0; i < 4; ++i)
#pragma unroll
      for (int j = 0; j < 4; ++j)
#pragma unroll
        for (int r = 0; r < 4; ++r)
          HL[hwo + i * 2176 + r * 136 + j * 16] = f2bf(gelu_f(acc1[i][j][r]));

    // ---- phase 2: acc2 += gelu(chunk) * W2 slice, K=128 in 4 slices ----
#pragma unroll
    for (int s = 0; s < 4; ++s) {
      __syncthreads();                         // HL writes + W2 slice staged
      if (s < 3) {
        short* wb = ((s + 1) & 1) ? Ws1 : Ws0;
#pragma unroll
        for (int c = 0; c < 2; ++c)
          async_cp16(w2g[c] + hc * 256 + (s + 1) * 64, wb + ldso[c]);
      }
      const short* wb = (s & 1) ? Ws1 : Ws0;
      bf16x8 af[4], bfr[4];
#pragma unroll
      for (int t = 0; t < 4; ++t) af[t]  = *(const bf16x8*)(HL + hro + t * 2176 + s * 32);
#pragma unroll
      for (int t = 0; t < 4; ++t) bfr[t] = *(const bf16x8*)(wb + boff + t * 512);
#pragma unroll
      for (int i = 0; i < 4; ++i)
#pragma unroll
        for (int j = 0; j < 4; ++j)
          acc2[i][j] = __builtin_amdgcn_mfma_f32_16x16x32_bf16(af[i], bfr[j], acc2[i][j], 0, 0, 0);
    }

    if (hc < 3) {
      __syncthreads();   // ALIAS GUARD: HL reads done before staging into Xs0
#pragma unroll
      for (int c = 0; c < 2; ++c) {
        async_cp16(xg[c],                              Xs0 + ldso[c]);
        async_cp16(w1g[c] + (size_t)(hc + 1) * 131072, Ws0 + ldso[c]);
      }
    }
  }

  // ---- epilogue ----
  const int d4 = wn * 64 + lm;
  const int lqr = (l >> 4) * 4;
  if (staged) {  // coalesced bf16: OUTs[e][row][d4]
    unsigned short* Ob = (unsigned short*)O;
    const size_t base = ((size_t)e * 8192 + tile * 128 + wm * 64 + lqr) * 128 + d4;
#pragma unroll
    for (int i = 0; i < 4; ++i)
#pragma unroll
      for (int r = 0; r < 4; ++r)
#pragma unroll
        for (int j = 0; j < 4; ++j)
          Ob[base + (size_t)(i * 16 + r) * 128 + j * 16] = (unsigned short)f2bf(acc2[i][j][r]);
  } else {       // direct strided fp32 fallback
    float* Of = (float*)O;
    const size_t rowb = (size_t)tile * 128 + wm * 64 + lqr;
    const size_t base = (rowb * 128 + d4) * 16 + e;
#pragma unroll
    for (int i = 0; i < 4; ++i)
#pragma unroll
      for (int r = 0; r < 4; ++r)
#pragma unroll
        for (int j = 0; j < 4; ++j)
          Of[base + (size_t)(i * 16 + r) * 2048 + j * 256] = acc2[i][j][r];
  }
}

// ---------------------------------------------------------------------------
// Permute: OUT[row][d4*16+e] (fp32) = OUTs[e][row][d4] (bf16). Block = 8 rows.
// ---------------------------------------------------------------------------
__global__ __launch_bounds__(256, 2)
void permute_kernel(const unsigned short* __restrict__ OUTs, float* __restrict__ OUT)
{
  __shared__ float T[8 * 16 * 132];     // 67.6 KB
  const int t = threadIdx.x;
  const int r0 = blockIdx.x * 8;
#pragma unroll
  for (int it = 0; it < 8; ++it) {
    int v = it * 256 + t;                       // bf16x8-id, [0,2048)
    int e = v >> 7, rem = v & 127, r = rem >> 4, q8 = rem & 15;
    bf16x8 d = *(const bf16x8*)(OUTs + ((size_t)e * 8192 + r0 + r) * 128 + q8 * 8);
#pragma unroll
    for (int u = 0; u < 8; ++u)
      T[(r * 16 + e) * 132 + q8 * 8 + u] =
          __uint_as_float(((uint32_t)(unsigned short)d[u]) << 16);
  }
  __syncthreads();
#pragma unroll
  for (int it = 0; it < 16; ++it) {
    int u = it * 256 + t;                       // vec4 id, [0,4096)
    int r = u >> 9;                             // [0,8)
    int c4 = (u & 511) * 4;                     // [0,2048)
    int d4 = c4 >> 4, e0 = c4 & 15;
    f32x4 o;
#pragma unroll
    for (int i = 0; i < 4; ++i) o[i] = T[(r * 16 + e0 + i) * 132 + d4];
    *(f32x4*)(OUT + (size_t)(r0 + r) * 2048 + c4) = o;
  }
}

extern "C" void kernel_launch(void* const* d_in, const int* in_sizes, int n_in,
                              void* d_out, int out_size, void* d_ws, size_t ws_size,
                              hipStream_t stream)
{
  const float* x  = (const float*)d_in[0];   // fp32 [8192][512]
  const float* w1 = (const float*)d_in[1];   // fp32 [16][512][512]
  const float* w2 = (const float*)d_in[2];   // fp32 [16][512][128]
  float* out = (float*)d_out;                // fp32 [8192][128][16]

  short* Xb  = (short*)d_ws;                 // 8.39 MB
  short* w1t = Xb + 4194304;                 // 8.39 MB
  short* w2t = w1t + 4194304;                // 2.10 MB
  unsigned short* OUTs = (unsigned short*)((char*)d_ws + 18874368);  // bf16, 33.5 MB
  const bool staged = ws_size >= 52428800ULL;

  prep_all<<<dim3(3328), 256, 0, stream>>>(x, w1, w2, Xb, w1t, w2t);
  moe_kernel<<<dim3(1024), 256, 0, stream>>>(Xb, w1t, w2t,
                                             staged ? (void*)OUTs : (void*)out,
                                             staged ? 1 : 0);
  if (staged)
    permute_kernel<<<dim3(1024), 256, 0, stream>>>(OUTs, out);
}